// Round 1
// baseline (59.437 us; speedup 1.0000x reference)
//
#include <hip/hip_runtime.h>

#define N_NODES 100000
#define N_EDGES 3200000

// ws layout (floats): [0..59] Weff (6 rows x 10: coeffs for e0,e1,s0,s1,d0,d1),
//                     [60..69] Ceff, ws_int[70] = "indices are int64" flag.

__global__ void setup_fold_kernel(const float* __restrict__ We, const float* __restrict__ be,
                                  const float* __restrict__ Wu, const float* __restrict__ bu,
                                  const int* __restrict__ ei32, float* __restrict__ ws) {
    int t = threadIdx.x;
    if (t < 60) {
        int r = t / 10, h = t % 10;
        float v;
        if (r < 2) {
            v = 0.0f;
            #pragma unroll
            for (int k = 0; k < 10; ++k) v = fmaf(We[r * 10 + k], Wu[k * 10 + h], v);
        } else {
            v = Wu[(10 + (r - 2)) * 10 + h];
        }
        ws[t] = v;
    } else if (t < 70) {
        int h = t - 60;
        float v = bu[h];
        #pragma unroll
        for (int k = 0; k < 10; ++k) v = fmaf(be[k], Wu[k * 10 + h], v);
        ws[t] = v;
    } else if (t == 70) {
        // If edge_index is physically int64 (little-endian, values < 2^31), every
        // odd int32 word is 0. Four genuine int32 indices all being 0 has prob ~1e-20.
        int flag = (ei32[1] == 0 && ei32[3] == 0 && ei32[5] == 0 && ei32[7] == 0) ? 1 : 0;
        ((int*)ws)[70] = flag;
    }
}

template <bool USE_WS>
__global__ __launch_bounds__(256) void gnn_main_kernel(
    const float* __restrict__ node, const float* __restrict__ edge,
    const int* __restrict__ ei,
    const float* __restrict__ We, const float* __restrict__ be,
    const float* __restrict__ Wu, const float* __restrict__ bu,
    const float* __restrict__ Wn, const float* __restrict__ bn,
    const float* __restrict__ ws,
    float* __restrict__ out, float* __restrict__ ef_out, int idx64_flag)
{
    int t = blockIdx.x * 256 + threadIdx.x;

    // ---- node branch: out = node @ Wn + bn (fused into first blocks) ----
    if (t < N_NODES) {
        float2 nf = ((const float2*)node)[t];
        float o0 = fmaf(nf.y, Wn[2], fmaf(nf.x, Wn[0], bn[0]));
        float o1 = fmaf(nf.y, Wn[3], fmaf(nf.x, Wn[1], bn[1]));
        ((float2*)out)[t] = make_float2(o0, o1);
    }
    if (t >= N_EDGES) return;

    int is64;
    if (USE_WS) is64 = ((const int*)ws)[70];
    else        is64 = idx64_flag;

    int row, col;
    if (is64) {
        row = ei[2 * t];
        col = ei[2 * (N_EDGES + t)];
    } else {
        row = ei[t];
        col = ei[N_EDGES + t];
    }

    float2 e = ((const float2*)edge)[t];
    float2 s = ((const float2*)node)[row];
    float2 d = ((const float2*)node)[col];

    float r[10];
    if (USE_WS) {
        #pragma unroll
        for (int h = 0; h < 10; ++h) {
            float acc = ws[60 + h];
            acc = fmaf(e.x, ws[0 * 10 + h], acc);
            acc = fmaf(e.y, ws[1 * 10 + h], acc);
            acc = fmaf(s.x, ws[2 * 10 + h], acc);
            acc = fmaf(s.y, ws[3 * 10 + h], acc);
            acc = fmaf(d.x, ws[4 * 10 + h], acc);
            acc = fmaf(d.y, ws[5 * 10 + h], acc);
            r[h] = acc;
        }
    } else {
        // direct (unfolded) path — all weight loads are uniform -> scalar loads
        float ef0[10];
        #pragma unroll
        for (int k = 0; k < 10; ++k)
            ef0[k] = fmaf(e.y, We[10 + k], fmaf(e.x, We[k], be[k]));
        #pragma unroll
        for (int h = 0; h < 10; ++h) {
            float acc = bu[h];
            #pragma unroll
            for (int k = 0; k < 10; ++k) acc = fmaf(ef0[k], Wu[k * 10 + h], acc);
            acc = fmaf(s.x, Wu[100 + h], acc);
            acc = fmaf(s.y, Wu[110 + h], acc);
            acc = fmaf(d.x, Wu[120 + h], acc);
            acc = fmaf(d.y, Wu[130 + h], acc);
            r[h] = acc;
        }
    }

    // ef row stride = 40 B -> 5 aligned float2 stores, region fully contiguous per wave
    float2* o = (float2*)(ef_out + (size_t)t * 10);
    o[0] = make_float2(r[0], r[1]);
    o[1] = make_float2(r[2], r[3]);
    o[2] = make_float2(r[4], r[5]);
    o[3] = make_float2(r[6], r[7]);
    o[4] = make_float2(r[8], r[9]);
}

// Fallback int64-detection when ws is unusable: done on device normally; this
// host-side path is never needed because flag lives in ws. (Kept simple.)

extern "C" void kernel_launch(void* const* d_in, const int* in_sizes, int n_in,
                              void* d_out, int out_size, void* d_ws, size_t ws_size,
                              hipStream_t stream) {
    const float* node = (const float*)d_in[0];
    const float* edge = (const float*)d_in[1];
    const int*   ei   = (const int*)d_in[2];
    const float* We   = (const float*)d_in[3];
    const float* be   = (const float*)d_in[4];
    const float* Wu   = (const float*)d_in[5];
    const float* bu   = (const float*)d_in[6];
    const float* Wn   = (const float*)d_in[7];
    const float* bn   = (const float*)d_in[8];

    float* out = (float*)d_out;
    float* ef  = out + 2 * (size_t)N_NODES;

    dim3 block(256);
    dim3 grid((N_EDGES + 255) / 256);

    if (ws_size >= 512) {
        float* ws = (float*)d_ws;
        hipLaunchKernelGGL(setup_fold_kernel, dim3(1), dim3(128), 0, stream,
                           We, be, Wu, bu, ei, ws);
        hipLaunchKernelGGL((gnn_main_kernel<true>), grid, block, 0, stream,
                           node, edge, ei, We, be, Wu, bu, Wn, bn, ws, out, ef, 0);
    } else {
        // No usable scratch: unfolded path; assume int32 indices per harness contract.
        hipLaunchKernelGGL((gnn_main_kernel<false>), grid, block, 0, stream,
                           node, edge, ei, We, be, Wu, bu, Wn, bn, nullptr, out, ef, 0);
    }
}

// Round 2
// 46.412 us; speedup vs baseline: 1.2806x; 1.2806x over previous
//
#include <hip/hip_runtime.h>

#define N_NODES 100000
#define N_EDGES 3200000
// 3200000 / 256 == 12500 exactly -> no tail block, barrier is uniform.

// ws layout (floats): [0..59] Weff (6 rows x 10: coeffs for e0,e1,s0,s1,d0,d1),
//                     [60..69] Ceff, ws_int[70] = "indices are int64" flag.

__global__ void setup_fold_kernel(const float* __restrict__ We, const float* __restrict__ be,
                                  const float* __restrict__ Wu, const float* __restrict__ bu,
                                  const int* __restrict__ ei32, float* __restrict__ ws) {
    int t = threadIdx.x;
    if (t < 60) {
        int r = t / 10, h = t % 10;
        float v;
        if (r < 2) {
            v = 0.0f;
            #pragma unroll
            for (int k = 0; k < 10; ++k) v = fmaf(We[r * 10 + k], Wu[k * 10 + h], v);
        } else {
            v = Wu[(10 + (r - 2)) * 10 + h];
        }
        ws[t] = v;
    } else if (t < 70) {
        int h = t - 60;
        float v = bu[h];
        #pragma unroll
        for (int k = 0; k < 10; ++k) v = fmaf(be[k], Wu[k * 10 + h], v);
        ws[t] = v;
    } else if (t == 70) {
        // int64 edge_index (LE, values < 2^31) -> every odd int32 word is 0.
        int flag = (ei32[1] == 0 && ei32[3] == 0 && ei32[5] == 0 && ei32[7] == 0) ? 1 : 0;
        ((int*)ws)[70] = flag;
    }
}

template <bool USE_WS>
__global__ __launch_bounds__(256) void gnn_main_kernel(
    const float* __restrict__ node, const float* __restrict__ edge,
    const int* __restrict__ ei,
    const float* __restrict__ We, const float* __restrict__ be,
    const float* __restrict__ Wu, const float* __restrict__ bu,
    const float* __restrict__ Wn, const float* __restrict__ bn,
    const float* __restrict__ ws,
    float* __restrict__ out, float* __restrict__ ef_out, int idx64_flag)
{
    __shared__ float lds[2560];          // 256 edges x 10 floats = 10240 B
    const int tid = threadIdx.x;
    const int t = blockIdx.x * 256 + tid;

    // ---- node branch: out = node @ Wn + bn (fused into first blocks) ----
    if (t < N_NODES) {
        float2 nf = ((const float2*)node)[t];
        float o0 = fmaf(nf.y, Wn[2], fmaf(nf.x, Wn[0], bn[0]));
        float o1 = fmaf(nf.y, Wn[3], fmaf(nf.x, Wn[1], bn[1]));
        ((float2*)out)[t] = make_float2(o0, o1);
    }
    // grid is exact: t < N_EDGES for every thread.

    int is64;
    if (USE_WS) is64 = ((const int*)ws)[70];
    else        is64 = idx64_flag;

    int row, col;
    if (is64) {
        row = ei[2 * t];
        col = ei[2 * (N_EDGES + t)];
    } else {
        row = ei[t];
        col = ei[N_EDGES + t];
    }

    float2 e = ((const float2*)edge)[t];
    float2 s = ((const float2*)node)[row];
    float2 d = ((const float2*)node)[col];

    float r[10];
    if (USE_WS) {
        #pragma unroll
        for (int h = 0; h < 10; ++h) {
            float acc = ws[60 + h];
            acc = fmaf(e.x, ws[0 * 10 + h], acc);
            acc = fmaf(e.y, ws[1 * 10 + h], acc);
            acc = fmaf(s.x, ws[2 * 10 + h], acc);
            acc = fmaf(s.y, ws[3 * 10 + h], acc);
            acc = fmaf(d.x, ws[4 * 10 + h], acc);
            acc = fmaf(d.y, ws[5 * 10 + h], acc);
            r[h] = acc;
        }
    } else {
        float ef0[10];
        #pragma unroll
        for (int k = 0; k < 10; ++k)
            ef0[k] = fmaf(e.y, We[10 + k], fmaf(e.x, We[k], be[k]));
        #pragma unroll
        for (int h = 0; h < 10; ++h) {
            float acc = bu[h];
            #pragma unroll
            for (int k = 0; k < 10; ++k) acc = fmaf(ef0[k], Wu[k * 10 + h], acc);
            acc = fmaf(s.x, Wu[100 + h], acc);
            acc = fmaf(s.y, Wu[110 + h], acc);
            acc = fmaf(d.x, Wu[120 + h], acc);
            acc = fmaf(d.y, Wu[130 + h], acc);
            r[h] = acc;
        }
    }

    // ---- stage in LDS, then fully-coalesced block-contiguous stores ----
    #pragma unroll
    for (int k = 0; k < 10; ++k) lds[tid * 10 + k] = r[k];
    __syncthreads();

    // block's output region: 2560 floats = 640 float4 (bytes 0..10239), contiguous
    float* gbase = ef_out + (size_t)blockIdx.x * 2560;
    const float4* l4 = (const float4*)lds;
    float4* g4 = (float4*)gbase;
    g4[tid]        = l4[tid];         // bytes     0.. 4095, coalesced
    g4[256 + tid]  = l4[256 + tid];   // bytes  4096.. 8191, coalesced
    const float2* l2 = (const float2*)lds;
    float2* g2 = (float2*)gbase;
    g2[1024 + tid] = l2[1024 + tid];  // bytes  8192..10239, coalesced
}

extern "C" void kernel_launch(void* const* d_in, const int* in_sizes, int n_in,
                              void* d_out, int out_size, void* d_ws, size_t ws_size,
                              hipStream_t stream) {
    const float* node = (const float*)d_in[0];
    const float* edge = (const float*)d_in[1];
    const int*   ei   = (const int*)d_in[2];
    const float* We   = (const float*)d_in[3];
    const float* be   = (const float*)d_in[4];
    const float* Wu   = (const float*)d_in[5];
    const float* bu   = (const float*)d_in[6];
    const float* Wn   = (const float*)d_in[7];
    const float* bn   = (const float*)d_in[8];

    float* out = (float*)d_out;
    float* ef  = out + 2 * (size_t)N_NODES;

    dim3 block(256);
    dim3 grid(N_EDGES / 256);   // 12500, exact

    if (ws_size >= 512) {
        float* ws = (float*)d_ws;
        hipLaunchKernelGGL(setup_fold_kernel, dim3(1), dim3(128), 0, stream,
                           We, be, Wu, bu, ei, ws);
        hipLaunchKernelGGL((gnn_main_kernel<true>), grid, block, 0, stream,
                           node, edge, ei, We, be, Wu, bu, Wn, bn, ws, out, ef, 0);
    } else {
        hipLaunchKernelGGL((gnn_main_kernel<false>), grid, block, 0, stream,
                           node, edge, ei, We, be, Wu, bu, Wn, bn, nullptr, out, ef, 0);
    }
}

// Round 4
// 44.953 us; speedup vs baseline: 1.3222x; 1.0325x over previous
//
#include <hip/hip_runtime.h>

#define N_NODES 100000
#define N_EDGES 3200000
// EPT=2: 6250 blocks * 256 threads * 2 edges = 3200000 exactly -> no tail.

typedef float f4_t __attribute__((ext_vector_type(4)));  // clang vector: ok for nontemporal builtins

// ws layout (floats): [0..59] Weff (6 rows x 10: coeffs for e0,e1,s0,s1,d0,d1),
//                     [60..69] Ceff, ws_int[70] = "indices are int64" flag.

__global__ void setup_fold_kernel(const float* __restrict__ We, const float* __restrict__ be,
                                  const float* __restrict__ Wu, const float* __restrict__ bu,
                                  const int* __restrict__ ei32, float* __restrict__ ws) {
    int t = threadIdx.x;
    if (t < 60) {
        int r = t / 10, h = t % 10;
        float v;
        if (r < 2) {
            v = 0.0f;
            #pragma unroll
            for (int k = 0; k < 10; ++k) v = fmaf(We[r * 10 + k], Wu[k * 10 + h], v);
        } else {
            v = Wu[(10 + (r - 2)) * 10 + h];
        }
        ws[t] = v;
    } else if (t < 70) {
        int h = t - 60;
        float v = bu[h];
        #pragma unroll
        for (int k = 0; k < 10; ++k) v = fmaf(be[k], Wu[k * 10 + h], v);
        ws[t] = v;
    } else if (t == 70) {
        // int64 edge_index (LE, values < 2^31) -> every odd int32 word is 0.
        int flag = (ei32[1] == 0 && ei32[3] == 0 && ei32[5] == 0 && ei32[7] == 0) ? 1 : 0;
        ((int*)ws)[70] = flag;
    }
}

// ---- main: 2 edges/thread, padded LDS staging, coalesced nt float4 stores ----
__global__ __launch_bounds__(256) void gnn_main_kernel(
    const float* __restrict__ node, const float* __restrict__ edge,
    const int* __restrict__ ei,
    const float* __restrict__ Wn, const float* __restrict__ bn,
    const float* __restrict__ ws,
    float* __restrict__ out, float* __restrict__ ef_out)
{
    __shared__ float lds[256 * 21];      // stride 21: gcd(21,32)=1 -> <=2-way (free)
    const int tid = threadIdx.x;
    const int t = blockIdx.x * 256 + tid;     // pair index; edges 2t, 2t+1

    // ---- node branch (first 391 blocks): out = node @ Wn + bn ----
    if (t < N_NODES) {
        float2 nf = ((const float2*)node)[t];
        float o0 = fmaf(nf.y, Wn[2], fmaf(nf.x, Wn[0], bn[0]));
        float o1 = fmaf(nf.y, Wn[3], fmaf(nf.x, Wn[1], bn[1]));
        ((float2*)out)[t] = make_float2(o0, o1);
    }

    const int is64 = ((const int*)ws)[70];

    int row0, col0, row1, col1;
    if (is64) {
        int4 rr = ((const int4*)ei)[t];                                // int64 lows at .x,.z
        int4 cc = ((const int4*)(ei + 2 * (size_t)N_EDGES))[t];
        row0 = rr.x; row1 = rr.z; col0 = cc.x; col1 = cc.z;
    } else {
        int2 rr = ((const int2*)ei)[t];
        int2 cc = ((const int2*)(ei + (size_t)N_EDGES))[t];
        row0 = rr.x; row1 = rr.y; col0 = cc.x; col1 = cc.y;
    }

    float4 e01 = ((const float4*)edge)[t];   // edge 2t: (x,y), edge 2t+1: (z,w)
    float2 s0 = ((const float2*)node)[row0];
    float2 d0 = ((const float2*)node)[col0];
    float2 s1 = ((const float2*)node)[row1];
    float2 d1 = ((const float2*)node)[col1];

    float r[20];
    #pragma unroll
    for (int h = 0; h < 10; ++h) {
        float c  = ws[60 + h];
        float w0 = ws[h], w1 = ws[10 + h], w2 = ws[20 + h],
              w3 = ws[30 + h], w4 = ws[40 + h], w5 = ws[50 + h];
        float a0 = c, a1 = c;
        a0 = fmaf(e01.x, w0, a0);  a1 = fmaf(e01.z, w0, a1);
        a0 = fmaf(e01.y, w1, a0);  a1 = fmaf(e01.w, w1, a1);
        a0 = fmaf(s0.x,  w2, a0);  a1 = fmaf(s1.x,  w2, a1);
        a0 = fmaf(s0.y,  w3, a0);  a1 = fmaf(s1.y,  w3, a1);
        a0 = fmaf(d0.x,  w4, a0);  a1 = fmaf(d1.x,  w4, a1);
        a0 = fmaf(d0.y,  w5, a0);  a1 = fmaf(d1.y,  w5, a1);
        r[h] = a0; r[10 + h] = a1;
    }

    // stage: thread's 20 outputs at stride-21 (banks ~conflict-free)
    #pragma unroll
    for (int k = 0; k < 10; ++k) lds[tid * 21 + k] = r[k];
    #pragma unroll
    for (int k = 0; k < 10; ++k) lds[tid * 21 + 10 + k] = r[10 + k];
    __syncthreads();

    // block output span: 512 edges * 10 = 5120 floats = 1280 float4, contiguous.
    f4_t* g4 = (f4_t*)(ef_out + (size_t)blockIdx.x * 5120);
    #pragma unroll
    for (int v = 0; v < 5; ++v) {
        unsigned gidx = v * 256 + tid;        // float4 slot in block span
        unsigned p = gidx / 5u;               // source pair (thread) in LDS
        unsigned jj = gidx - 5u * p;          // float4-slot within that pair
        const float* src = &lds[p * 21 + 4 * jj];
        f4_t w = { src[0], src[1], src[2], src[3] };
        __builtin_nontemporal_store(w, &g4[gidx]);
    }
}

// Fallback (no usable ws): 1 edge/thread, unfolded weights, plain stores.
__global__ __launch_bounds__(256) void gnn_fallback_kernel(
    const float* __restrict__ node, const float* __restrict__ edge,
    const int* __restrict__ ei,
    const float* __restrict__ We, const float* __restrict__ be,
    const float* __restrict__ Wu, const float* __restrict__ bu,
    const float* __restrict__ Wn, const float* __restrict__ bn,
    float* __restrict__ out, float* __restrict__ ef_out)
{
    int t = blockIdx.x * 256 + threadIdx.x;
    if (t < N_NODES) {
        float2 nf = ((const float2*)node)[t];
        float o0 = fmaf(nf.y, Wn[2], fmaf(nf.x, Wn[0], bn[0]));
        float o1 = fmaf(nf.y, Wn[3], fmaf(nf.x, Wn[1], bn[1]));
        ((float2*)out)[t] = make_float2(o0, o1);
    }
    if (t >= N_EDGES) return;
    int row = ei[t], col = ei[N_EDGES + t];
    float2 e = ((const float2*)edge)[t];
    float2 s = ((const float2*)node)[row];
    float2 d = ((const float2*)node)[col];
    float ef0[10];
    #pragma unroll
    for (int k = 0; k < 10; ++k)
        ef0[k] = fmaf(e.y, We[10 + k], fmaf(e.x, We[k], be[k]));
    float* o = ef_out + (size_t)t * 10;
    #pragma unroll
    for (int h = 0; h < 10; ++h) {
        float acc = bu[h];
        #pragma unroll
        for (int k = 0; k < 10; ++k) acc = fmaf(ef0[k], Wu[k * 10 + h], acc);
        acc = fmaf(s.x, Wu[100 + h], acc);
        acc = fmaf(s.y, Wu[110 + h], acc);
        acc = fmaf(d.x, Wu[120 + h], acc);
        acc = fmaf(d.y, Wu[130 + h], acc);
        o[h] = acc;
    }
}

extern "C" void kernel_launch(void* const* d_in, const int* in_sizes, int n_in,
                              void* d_out, int out_size, void* d_ws, size_t ws_size,
                              hipStream_t stream) {
    const float* node = (const float*)d_in[0];
    const float* edge = (const float*)d_in[1];
    const int*   ei   = (const int*)d_in[2];
    const float* We   = (const float*)d_in[3];
    const float* be   = (const float*)d_in[4];
    const float* Wu   = (const float*)d_in[5];
    const float* bu   = (const float*)d_in[6];
    const float* Wn   = (const float*)d_in[7];
    const float* bn   = (const float*)d_in[8];

    float* out = (float*)d_out;
    float* ef  = out + 2 * (size_t)N_NODES;

    if (ws_size >= 512) {
        float* ws = (float*)d_ws;
        hipLaunchKernelGGL(setup_fold_kernel, dim3(1), dim3(128), 0, stream,
                           We, be, Wu, bu, ei, ws);
        hipLaunchKernelGGL(gnn_main_kernel, dim3(N_EDGES / 512), dim3(256), 0, stream,
                           node, edge, ei, Wn, bn, ws, out, ef);
    } else {
        hipLaunchKernelGGL(gnn_fallback_kernel, dim3((N_EDGES + 255) / 256), dim3(256), 0, stream,
                           node, edge, ei, We, be, Wu, bu, Wn, bn, out, ef);
    }
}

// Round 5
// 43.029 us; speedup vs baseline: 1.3813x; 1.0447x over previous
//
#include <hip/hip_runtime.h>

#define N_NODES 100000
#define N_EDGES 3200000
// EPT=2: 6250 blocks * 256 threads * 2 edges = 3200000 exactly -> no tail.

typedef float f4_t __attribute__((ext_vector_type(4)));

// Single fused kernel. Per block:
//   Phase A: issue edge load + node branch; threads 0..70 compute the folded
//            weights (Weff/Ceff of the 2-layer edge MLP) into LDS + int64 flag.
//   Phase B: index loads -> node gathers -> 60 FMA/edge MLP -> stage to LDS.
//   Phase C: block-contiguous coalesced nontemporal float4 stores.
// wf2 layout: wf2[8*h + j], j=0..5 -> Weff[j][h] (coeffs e0,e1,s0,s1,d0,d1), j=6 -> Ceff[h].
__global__ __launch_bounds__(256) void gnn_fused_kernel(
    const float* __restrict__ node, const float* __restrict__ edge,
    const int* __restrict__ ei,
    const float* __restrict__ We, const float* __restrict__ be,
    const float* __restrict__ Wu, const float* __restrict__ bu,
    const float* __restrict__ Wn, const float* __restrict__ bn,
    float* __restrict__ out, float* __restrict__ ef_out)
{
    __shared__ float wf2[80];        // 10 h-rows x 8 (6 weights + bias + pad), 32B/row
    __shared__ int   flagS;
    __shared__ float lds[256 * 21];  // stride 21: gcd(21,32)=1 -> <=2-way (free)

    const int tid = threadIdx.x;
    const int t = blockIdx.x * 256 + tid;     // pair index; edges 2t, 2t+1

    // ---- Phase A: loads that don't depend on the fold ----
    float4 e01 = ((const float4*)edge)[t];    // edge 2t: (x,y), edge 2t+1: (z,w)

    if (t < N_NODES) {                        // node branch: out = node @ Wn + bn
        float2 nf = ((const float2*)node)[t];
        float o0 = fmaf(nf.y, Wn[2], fmaf(nf.x, Wn[0], bn[0]));
        float o1 = fmaf(nf.y, Wn[3], fmaf(nf.x, Wn[1], bn[1]));
        ((float2*)out)[t] = make_float2(o0, o1);
    }

    // ---- fold: Weff = [We@Wu_e ; Wu_nodes], Ceff = be@Wu_e + bu ----
    if (tid < 60) {
        int r = tid / 10, h = tid % 10;       // r: input slot (e0,e1,s0,s1,d0,d1)
        float v;
        if (r < 2) {
            v = 0.0f;
            #pragma unroll
            for (int k = 0; k < 10; ++k) v = fmaf(We[r * 10 + k], Wu[k * 10 + h], v);
        } else {
            v = Wu[(10 + (r - 2)) * 10 + h];
        }
        wf2[8 * h + r] = v;
    } else if (tid < 70) {
        int h = tid - 60;
        float v = bu[h];
        #pragma unroll
        for (int k = 0; k < 10; ++k) v = fmaf(be[k], Wu[k * 10 + h], v);
        wf2[8 * h + 6] = v;
    } else if (tid == 70) {
        // int64 edge_index (LE, values < 2^31) -> every odd int32 word is 0.
        flagS = (ei[1] == 0 && ei[3] == 0 && ei[5] == 0 && ei[7] == 0) ? 1 : 0;
    }
    __syncthreads();

    // ---- Phase B: indices, gathers, MLP ----
    const int is64 = flagS;
    int row0, col0, row1, col1;
    if (is64) {
        int4 rr = ((const int4*)ei)[t];                       // int64 lows at .x,.z
        int4 cc = ((const int4*)(ei + 2 * (size_t)N_EDGES))[t];
        row0 = rr.x; row1 = rr.z; col0 = cc.x; col1 = cc.z;
    } else {
        int2 rr = ((const int2*)ei)[t];
        int2 cc = ((const int2*)(ei + (size_t)N_EDGES))[t];
        row0 = rr.x; row1 = rr.y; col0 = cc.x; col1 = cc.y;
    }

    float2 s0 = ((const float2*)node)[row0];
    float2 d0 = ((const float2*)node)[col0];
    float2 s1 = ((const float2*)node)[row1];
    float2 d1 = ((const float2*)node)[col1];

    float r[20];
    #pragma unroll
    for (int h = 0; h < 10; ++h) {
        const f4_t* wv = (const f4_t*)&wf2[8 * h];   // 32B-aligned -> 2x ds_read_b128 broadcast
        f4_t wa = wv[0];                              // w0,w1,w2,w3
        f4_t wb = wv[1];                              // w4,w5,c,pad
        float a0 = wb.z, a1 = wb.z;
        a0 = fmaf(e01.x, wa.x, a0);  a1 = fmaf(e01.z, wa.x, a1);
        a0 = fmaf(e01.y, wa.y, a0);  a1 = fmaf(e01.w, wa.y, a1);
        a0 = fmaf(s0.x,  wa.z, a0);  a1 = fmaf(s1.x,  wa.z, a1);
        a0 = fmaf(s0.y,  wa.w, a0);  a1 = fmaf(s1.y,  wa.w, a1);
        a0 = fmaf(d0.x,  wb.x, a0);  a1 = fmaf(d1.x,  wb.x, a1);
        a0 = fmaf(d0.y,  wb.y, a0);  a1 = fmaf(d1.y,  wb.y, a1);
        r[h] = a0; r[10 + h] = a1;
    }

    // stage: thread's 20 outputs at stride-21 (banks ~conflict-free)
    #pragma unroll
    for (int k = 0; k < 10; ++k) lds[tid * 21 + k] = r[k];
    #pragma unroll
    for (int k = 0; k < 10; ++k) lds[tid * 21 + 10 + k] = r[10 + k];
    __syncthreads();

    // ---- Phase C: block output span 512 edges * 10 = 5120 floats, contiguous ----
    f4_t* g4 = (f4_t*)(ef_out + (size_t)blockIdx.x * 5120);
    #pragma unroll
    for (int v = 0; v < 5; ++v) {
        unsigned gidx = v * 256 + tid;        // float4 slot in block span
        unsigned p = gidx / 5u;               // source pair (thread) in LDS
        unsigned jj = gidx - 5u * p;          // float4-slot within that pair
        const float* src = &lds[p * 21 + 4 * jj];
        f4_t w = { src[0], src[1], src[2], src[3] };
        __builtin_nontemporal_store(w, &g4[gidx]);
    }
}

extern "C" void kernel_launch(void* const* d_in, const int* in_sizes, int n_in,
                              void* d_out, int out_size, void* d_ws, size_t ws_size,
                              hipStream_t stream) {
    const float* node = (const float*)d_in[0];
    const float* edge = (const float*)d_in[1];
    const int*   ei   = (const int*)d_in[2];
    const float* We   = (const float*)d_in[3];
    const float* be   = (const float*)d_in[4];
    const float* Wu   = (const float*)d_in[5];
    const float* bu   = (const float*)d_in[6];
    const float* Wn   = (const float*)d_in[7];
    const float* bn   = (const float*)d_in[8];

    float* out = (float*)d_out;
    float* ef  = out + 2 * (size_t)N_NODES;

    hipLaunchKernelGGL(gnn_fused_kernel, dim3(N_EDGES / 512), dim3(256), 0, stream,
                       node, edge, ei, We, be, Wu, bu, Wn, bn, out, ef);
}